// Round 9
// baseline (246.524 us; speedup 1.0000x reference)
//
#include <hip/hip_runtime.h>
#include <limits.h>
#include <math.h>

#define GRID 64
#define NUM_VOXELS (GRID * GRID * GRID)   // 262144
#define KSLOTS 16
#define CAP 32                            // per-voxel scratch capacity
#define FEAT 29

typedef float f32x4 __attribute__((ext_vector_type(4)));

// Pass 1: scatter packed (conf,pid) keys into per-voxel lists.
// 4 points per thread: 3x f32x4 pts loads + 1x f32x4 conf load (coalesced),
// then 4 independent atomic->store chains (MLP hides atomic latency).
// Key = (conf_bits << 32) | ~pid; MAX key == (conf desc, pid asc) — matches
// the reference's stable double-sort, independent of atomic arrival order.
// Binning: XLA folds (p - MIN)/0.02 -> (p - MIN) * 50.0f exactly; must use
// the multiply (NOT an IEEE divide) to match floor() at voxel boundaries.
__global__ __launch_bounds__(256) void scatter_kernel(
    const float* __restrict__ pts, const float* __restrict__ conf, int n,
    int* __restrict__ cnt, unsigned long long* __restrict__ buf) {
    const int base = (blockIdx.x * blockDim.x + threadIdx.x) * 4;
    if (base >= n) return;
    const float minc = (float)(-(64.0 * 0.02) / 2.0);  // -0.63999998569488525f
    const float rinv = 50.0f;                          // fold(1/0.02f) == 50.0f

    float px[4], py[4], pz[4], pc[4];
    if (base + 4 <= n) {
        const f32x4* p4 = (const f32x4*)(pts + (size_t)base * 3);  // 48B-aligned
        f32x4 a = p4[0];   // x0 y0 z0 x1
        f32x4 b = p4[1];   // y1 z1 x2 y2
        f32x4 c = p4[2];   // z2 x3 y3 z3
        f32x4 cf = *(const f32x4*)(conf + base);
        px[0] = a.x; py[0] = a.y; pz[0] = a.z;
        px[1] = a.w; py[1] = b.x; pz[1] = b.y;
        px[2] = b.z; py[2] = b.w; pz[2] = c.x;
        px[3] = c.y; py[3] = c.z; pz[3] = c.w;
        pc[0] = cf.x; pc[1] = cf.y; pc[2] = cf.z; pc[3] = cf.w;
    } else {
        #pragma unroll
        for (int j = 0; j < 4; ++j) {
            int i = base + j;
            if (i < n) {
                px[j] = pts[(size_t)i * 3 + 0];
                py[j] = pts[(size_t)i * 3 + 1];
                pz[j] = pts[(size_t)i * 3 + 2];
                pc[j] = conf[i];
            } else {
                px[j] = 1e9f; py[j] = 1e9f; pz[j] = 1e9f; pc[j] = 0.0f;
            }
        }
    }

    #pragma unroll
    for (int j = 0; j < 4; ++j) {
        int ix = (int)floorf((px[j] - minc) * rinv);
        int iy = (int)floorf((py[j] - minc) * rinv);
        int iz = (int)floorf((pz[j] - minc) * rinv);
        if ((unsigned)ix >= GRID || (unsigned)iy >= GRID || (unsigned)iz >= GRID)
            continue;
        int v = ix * (GRID * GRID) + iy * GRID + iz;
        int pos = atomicAdd(&cnt[v], 1);
        if (pos < CAP) {
            int i = base + j;
            unsigned long long key =
                ((unsigned long long)__float_as_uint(pc[j]) << 32) |
                (unsigned int)(~i);
            buf[(size_t)v * CAP + pos] = key;
        }
    }
}

// Pass 2: one THREAD per voxel. Top-16 by key via unrolled 16-deep
// compare-swap insertion; empty sentinel 0. Output as 4x 16B stores.
__global__ __launch_bounds__(256) void select_kernel(
    const int* __restrict__ cnt, const unsigned long long* __restrict__ buf,
    float* __restrict__ out_idx) {
    int v = blockIdx.x * blockDim.x + threadIdx.x;
    if (v >= NUM_VOXELS) return;
    unsigned long long top[KSLOTS];
    #pragma unroll
    for (int s = 0; s < KSLOTS; ++s) top[s] = 0ULL;
    int n = cnt[v];
    if (n > CAP) n = CAP;
    const unsigned long long* row = buf + (size_t)v * CAP;
    for (int j = 0; j < n; ++j) {
        unsigned long long key = row[j];
        #pragma unroll
        for (int s = 0; s < KSLOTS; ++s) {
            unsigned long long hi = key > top[s] ? key : top[s];
            unsigned long long lo = key > top[s] ? top[s] : key;
            top[s] = hi;
            key    = lo;
        }
    }
    f32x4* o4 = (f32x4*)(out_idx + (size_t)v * KSLOTS);  // 64B-aligned
    #pragma unroll
    for (int q = 0; q < 4; ++q) {
        f32x4 w;
        #pragma unroll
        for (int r = 0; r < 4; ++r) {
            unsigned long long k = top[q * 4 + r];
            w[r] = (float)((k != 0ULL) ? (int)(~(unsigned int)k) : -1);
        }
        o4[q] = w;
    }
}

// Pass 3: feature gather, thread-per-slot. Cached vector loads (desc via
// 6x 16B), LDS staging, NT streaming stores for the 479MB output.
__global__ __launch_bounds__(256) void gather_kernel(
    const float* __restrict__ pts, const float* __restrict__ conf,
    const float* __restrict__ desc, const float* __restrict__ desc_conf,
    const float* __restrict__ out_idx, float* __restrict__ out_feat) {
    const int t = threadIdx.x;
    const size_t slot0 = (size_t)blockIdx.x * 256;
    const size_t slot  = slot0 + t;
    __shared__ __align__(16) float st[256 * FEAT];   // 29696 B
    int pid = (int)out_idx[slot];
    float f[FEAT];
    #pragma unroll
    for (int e = 0; e < FEAT; ++e) f[e] = 0.0f;
    if (pid >= 0) {
        f[0] = pts[(size_t)pid * 3 + 0];
        f[1] = pts[(size_t)pid * 3 + 1];
        f[2] = pts[(size_t)pid * 3 + 2];
        f[3] = conf[pid];
        const f32x4* d4 = (const f32x4*)(desc) + (size_t)pid * 6;  // 96B rows
        #pragma unroll
        for (int q = 0; q < 6; ++q) {
            f32x4 d = d4[q];
            f[4 + q * 4 + 0] = d.x; f[4 + q * 4 + 1] = d.y;
            f[4 + q * 4 + 2] = d.z; f[4 + q * 4 + 3] = d.w;
        }
        f[28] = desc_conf[pid];
    }
    #pragma unroll
    for (int e = 0; e < FEAT; ++e) st[t * FEAT + e] = f[e];
    __syncthreads();
    f32x4* dst = (f32x4*)(out_feat + slot0 * FEAT);
    const f32x4* src = (const f32x4*)st;
    #pragma unroll
    for (int k = t; k < 256 * FEAT / 4; k += 256)
        __builtin_nontemporal_store(src[k], &dst[k]);
}

extern "C" void kernel_launch(void* const* d_in, const int* in_sizes, int n_in,
                              void* d_out, int out_size, void* d_ws, size_t ws_size,
                              hipStream_t stream) {
    const float* pts       = (const float*)d_in[0];
    const float* conf      = (const float*)d_in[1];
    const float* desc      = (const float*)d_in[2];
    const float* desc_conf = (const float*)d_in[3];
    const int n = in_sizes[1];  // conf is (N,)

    float* out_idx  = (float*)d_out;                         // (V,16) as float
    float* out_feat = out_idx + (size_t)NUM_VOXELS * KSLOTS; // (V,16,29)

    const size_t need = (size_t)NUM_VOXELS * 4              // cnt (1 MB)
                      + (size_t)NUM_VOXELS * CAP * 8;       // buf (64 MB)

    int* cnt;
    unsigned long long* buf;
    if (ws_size >= need) {
        cnt = (int*)d_ws;
        buf = (unsigned long long*)((char*)d_ws + (size_t)NUM_VOXELS * 4);
    } else {
        // Fallback: scratch at the head of the X region (gather rewrites it
        // deterministically afterwards).
        cnt = (int*)out_feat;
        buf = (unsigned long long*)(out_feat + NUM_VOXELS);
    }

    (void)hipMemsetAsync(cnt, 0, NUM_VOXELS * sizeof(int), stream);
    const int pts_per_blk = 256 * 4;
    scatter_kernel<<<(n + pts_per_blk - 1) / pts_per_blk, 256, 0, stream>>>(
        pts, conf, n, cnt, buf);
    select_kernel<<<NUM_VOXELS / 256, 256, 0, stream>>>(cnt, buf, out_idx);
    gather_kernel<<<(NUM_VOXELS * KSLOTS) / 256, 256, 0, stream>>>(
        pts, conf, desc, desc_conf, out_idx, out_feat);
}

// Round 10
// 226.354 us; speedup vs baseline: 1.0891x; 1.0891x over previous
//
#include <hip/hip_runtime.h>
#include <limits.h>
#include <math.h>

#define GRID 64
#define NUM_VOXELS (GRID * GRID * GRID)   // 262144
#define KSLOTS 16
#define CAP 32                            // per-voxel scratch capacity
#define FEAT 29

typedef float f32x4 __attribute__((ext_vector_type(4)));

// Pass 1: scatter packed (conf,pid) keys into per-voxel lists (round-8 form:
// 1 point/thread — 4x batching regressed in round 9 by cutting wave count).
// Key = (conf_bits << 32) | ~pid. conf >= 0 so conf_bits is monotonic in
// value; MAX key == (conf desc, pid asc) — the reference's stable double-sort
// order, deterministic regardless of atomic arrival order.
// Binning: XLA folds (p - MIN)/0.02 -> (p - MIN) * 50.0f exactly; must use
// the multiply (NOT an IEEE divide) to match floor() at voxel boundaries.
__global__ __launch_bounds__(256) void scatter_kernel(
    const float* __restrict__ pts, const float* __restrict__ conf, int n,
    int* __restrict__ cnt, unsigned long long* __restrict__ buf) {
    int i = blockIdx.x * blockDim.x + threadIdx.x;
    if (i >= n) return;
    const float minc = (float)(-(64.0 * 0.02) / 2.0);  // -0.63999998569488525f
    const float rinv = 50.0f;                          // fold(1/0.02f) == 50.0f
    float x = pts[(size_t)i * 3 + 0];
    float y = pts[(size_t)i * 3 + 1];
    float z = pts[(size_t)i * 3 + 2];
    int ix = (int)floorf((x - minc) * rinv);
    int iy = (int)floorf((y - minc) * rinv);
    int iz = (int)floorf((z - minc) * rinv);
    if ((unsigned)ix >= GRID || (unsigned)iy >= GRID || (unsigned)iz >= GRID) return;
    int v = ix * (GRID * GRID) + iy * GRID + iz;
    int pos = atomicAdd(&cnt[v], 1);
    if (pos < CAP) {
        unsigned int cb = __float_as_uint(conf[i]);
        unsigned long long key =
            ((unsigned long long)cb << 32) | (unsigned int)(~i);
        buf[(size_t)v * CAP + pos] = key;
    }
}

// Pass 2: one THREAD per voxel. Top-16 by key via unrolled 16-deep
// compare-swap insertion; empty sentinel 0. Also stages each slot's conf
// (recovered EXACTLY from the key's high 32 bits) into stagedC so gather
// never needs the random conf[pid] line fetch.
__global__ __launch_bounds__(256) void select_kernel(
    const int* __restrict__ cnt, const unsigned long long* __restrict__ buf,
    float* __restrict__ out_idx, float* __restrict__ stagedC) {
    int v = blockIdx.x * blockDim.x + threadIdx.x;
    if (v >= NUM_VOXELS) return;
    unsigned long long top[KSLOTS];
    #pragma unroll
    for (int s = 0; s < KSLOTS; ++s) top[s] = 0ULL;
    int n = cnt[v];
    if (n > CAP) n = CAP;
    const unsigned long long* row = buf + (size_t)v * CAP;
    for (int j = 0; j < n; ++j) {
        unsigned long long key = row[j];
        #pragma unroll
        for (int s = 0; s < KSLOTS; ++s) {
            unsigned long long hi = key > top[s] ? key : top[s];
            unsigned long long lo = key > top[s] ? top[s] : key;
            top[s] = hi;
            key    = lo;
        }
    }
    float* o = out_idx + (size_t)v * KSLOTS;
    float* c = stagedC + (size_t)v * KSLOTS;
    #pragma unroll
    for (int s = 0; s < KSLOTS; ++s) {
        unsigned long long k = top[s];
        o[s] = (float)((k != 0ULL) ? (int)(~(unsigned int)k) : -1);
        c[s] = __uint_as_float((unsigned int)(k >> 32));  // exact conf bits; 0.0 if empty
    }
}

// Pass 3: feature gather, thread-per-slot. Cached vector loads (desc via
// 6x 16B), conf from stagedC (coalesced), LDS staging, NT streaming stores.
__global__ __launch_bounds__(256) void gather_kernel(
    const float* __restrict__ pts, const float* __restrict__ stagedC,
    const float* __restrict__ desc, const float* __restrict__ desc_conf,
    const float* __restrict__ out_idx, float* __restrict__ out_feat) {
    const int t = threadIdx.x;
    const size_t slot0 = (size_t)blockIdx.x * 256;
    const size_t slot  = slot0 + t;
    __shared__ __align__(16) float st[256 * FEAT];   // 29696 B
    int pid = (int)out_idx[slot];
    float f[FEAT];
    #pragma unroll
    for (int e = 0; e < FEAT; ++e) f[e] = 0.0f;
    if (pid >= 0) {
        f[0] = pts[(size_t)pid * 3 + 0];
        f[1] = pts[(size_t)pid * 3 + 1];
        f[2] = pts[(size_t)pid * 3 + 2];
        f[3] = stagedC[slot];                        // exact conf via key bits
        const f32x4* d4 = (const f32x4*)(desc) + (size_t)pid * 6;  // 96B rows
        #pragma unroll
        for (int q = 0; q < 6; ++q) {
            f32x4 d = d4[q];
            f[4 + q * 4 + 0] = d.x; f[4 + q * 4 + 1] = d.y;
            f[4 + q * 4 + 2] = d.z; f[4 + q * 4 + 3] = d.w;
        }
        f[28] = desc_conf[pid];
    }
    #pragma unroll
    for (int e = 0; e < FEAT; ++e) st[t * FEAT + e] = f[e];
    __syncthreads();
    f32x4* dst = (f32x4*)(out_feat + slot0 * FEAT);
    const f32x4* src = (const f32x4*)st;
    #pragma unroll
    for (int k = t; k < 256 * FEAT / 4; k += 256)
        __builtin_nontemporal_store(src[k], &dst[k]);
}

// ---- Fallback gather (no stagedC) if d_ws is too small: round-8 form ----
__global__ __launch_bounds__(256) void select_kernel_nf(
    const int* __restrict__ cnt, const unsigned long long* __restrict__ buf,
    float* __restrict__ out_idx) {
    int v = blockIdx.x * blockDim.x + threadIdx.x;
    if (v >= NUM_VOXELS) return;
    unsigned long long top[KSLOTS];
    #pragma unroll
    for (int s = 0; s < KSLOTS; ++s) top[s] = 0ULL;
    int n = cnt[v];
    if (n > CAP) n = CAP;
    const unsigned long long* row = buf + (size_t)v * CAP;
    for (int j = 0; j < n; ++j) {
        unsigned long long key = row[j];
        #pragma unroll
        for (int s = 0; s < KSLOTS; ++s) {
            unsigned long long hi = key > top[s] ? key : top[s];
            unsigned long long lo = key > top[s] ? top[s] : key;
            top[s] = hi;
            key    = lo;
        }
    }
    float* o = out_idx + (size_t)v * KSLOTS;
    #pragma unroll
    for (int s = 0; s < KSLOTS; ++s) {
        unsigned long long k = top[s];
        o[s] = (float)((k != 0ULL) ? (int)(~(unsigned int)k) : -1);
    }
}

__global__ __launch_bounds__(256) void gather_kernel_nf(
    const float* __restrict__ pts, const float* __restrict__ conf,
    const float* __restrict__ desc, const float* __restrict__ desc_conf,
    const float* __restrict__ out_idx, float* __restrict__ out_feat) {
    const int t = threadIdx.x;
    const size_t slot0 = (size_t)blockIdx.x * 256;
    const size_t slot  = slot0 + t;
    __shared__ __align__(16) float st[256 * FEAT];
    int pid = (int)out_idx[slot];
    float f[FEAT];
    #pragma unroll
    for (int e = 0; e < FEAT; ++e) f[e] = 0.0f;
    if (pid >= 0) {
        f[0] = pts[(size_t)pid * 3 + 0];
        f[1] = pts[(size_t)pid * 3 + 1];
        f[2] = pts[(size_t)pid * 3 + 2];
        f[3] = conf[pid];
        const f32x4* d4 = (const f32x4*)(desc) + (size_t)pid * 6;
        #pragma unroll
        for (int q = 0; q < 6; ++q) {
            f32x4 d = d4[q];
            f[4 + q * 4 + 0] = d.x; f[4 + q * 4 + 1] = d.y;
            f[4 + q * 4 + 2] = d.z; f[4 + q * 4 + 3] = d.w;
        }
        f[28] = desc_conf[pid];
    }
    #pragma unroll
    for (int e = 0; e < FEAT; ++e) st[t * FEAT + e] = f[e];
    __syncthreads();
    f32x4* dst = (f32x4*)(out_feat + slot0 * FEAT);
    const f32x4* src = (const f32x4*)st;
    #pragma unroll
    for (int k = t; k < 256 * FEAT / 4; k += 256)
        __builtin_nontemporal_store(src[k], &dst[k]);
}

extern "C" void kernel_launch(void* const* d_in, const int* in_sizes, int n_in,
                              void* d_out, int out_size, void* d_ws, size_t ws_size,
                              hipStream_t stream) {
    const float* pts       = (const float*)d_in[0];
    const float* conf      = (const float*)d_in[1];
    const float* desc      = (const float*)d_in[2];
    const float* desc_conf = (const float*)d_in[3];
    const int n = in_sizes[1];  // conf is (N,)

    float* out_idx  = (float*)d_out;                         // (V,16) as float
    float* out_feat = out_idx + (size_t)NUM_VOXELS * KSLOTS; // (V,16,29)

    const size_t sz_cnt  = (size_t)NUM_VOXELS * 4;           // 1 MB
    const size_t sz_buf  = (size_t)NUM_VOXELS * CAP * 8;     // 64 MB
    const size_t sz_stgc = (size_t)NUM_VOXELS * KSLOTS * 4;  // 16 MB

    if (ws_size >= sz_cnt + sz_buf + sz_stgc) {
        int* cnt = (int*)d_ws;
        unsigned long long* buf = (unsigned long long*)((char*)d_ws + sz_cnt);
        float* stagedC = (float*)((char*)d_ws + sz_cnt + sz_buf);
        (void)hipMemsetAsync(cnt, 0, sz_cnt, stream);
        scatter_kernel<<<(n + 255) / 256, 256, 0, stream>>>(pts, conf, n, cnt, buf);
        select_kernel<<<NUM_VOXELS / 256, 256, 0, stream>>>(cnt, buf, out_idx, stagedC);
        gather_kernel<<<(NUM_VOXELS * KSLOTS) / 256, 256, 0, stream>>>(
            pts, stagedC, desc, desc_conf, out_idx, out_feat);
    } else {
        // Fallback: scratch at head of X region (rewritten by gather), no staging.
        int* cnt = (int*)out_feat;
        unsigned long long* buf = (unsigned long long*)(out_feat + NUM_VOXELS);
        (void)hipMemsetAsync(cnt, 0, sz_cnt, stream);
        scatter_kernel<<<(n + 255) / 256, 256, 0, stream>>>(pts, conf, n, cnt, buf);
        select_kernel_nf<<<NUM_VOXELS / 256, 256, 0, stream>>>(cnt, buf, out_idx);
        gather_kernel_nf<<<(NUM_VOXELS * KSLOTS) / 256, 256, 0, stream>>>(
            pts, conf, desc, desc_conf, out_idx, out_feat);
    }
}